// Round 2
// baseline (1062.847 us; speedup 1.0000x reference)
//
#include <hip/hip_runtime.h>
#include <stdint.h>

#define BB 8192
#define TT 512
#define FF 24
#define HH 12

#define NCHAIN 64          // chains per block (= consumer wave lanes)
#define TC 8               // timesteps per chunk
#define NCHUNK (TT / TC)   // 64
#define ROWF 13            // floats per (chain,t) row in LDS (12 + 1 pad)
#define CHSTRIDE (TC * ROWF + 1)  // 105 floats per chain per chunk (odd -> conflict-free)
#define BUFN (NCHAIN * CHSTRIDE)  // 6720 floats per buffer

typedef float v2f __attribute__((ext_vector_type(2)));

__device__ __forceinline__ float fast_tanh(float x) {
  // tanh(x) = 1 - 2/(exp(2x)+1); saturates correctly at +/-inf, NaN-free
  float e = __expf(x + x);
  float r = __builtin_amdgcn_rcpf(e + 1.0f);
  return fmaf(-2.0f, r, 1.0f);
}

__global__ __launch_bounds__(256, 1) void rnn_pc(
    const float* __restrict__ x, const float* __restrict__ W_ih,
    const float* __restrict__ b_ih, const float* __restrict__ W_hh,
    const float* __restrict__ b_hh, const float* __restrict__ W1,
    const float* __restrict__ b1, const float* __restrict__ W2,
    const float* __restrict__ b2, const float* __restrict__ W3,
    const float* __restrict__ b3, float* __restrict__ out) {
  __shared__ float xpb[2][BUFN];  // 53.8 KB

  const int tid  = threadIdx.x;
  const int wid  = tid >> 6;   // 0..2 producers, 3 consumer
  const int lane = tid & 63;
  const int bid  = blockIdx.x;

  if (wid < 3) {
    // ================= PRODUCER: xp = x @ W_ih^T + (b_ih + b_hh) =================
    const int jbase = wid * 4;  // this wave owns h-outputs jbase..jbase+3
    v2f wih[4][12];
    float bs[4];
#pragma unroll
    for (int r = 0; r < 4; ++r) {
      bs[r] = b_ih[jbase + r] + b_hh[jbase + r];
#pragma unroll
      for (int k = 0; k < 12; ++k)
        wih[r][k] = *(const v2f*)(W_ih + (jbase + r) * FF + 2 * k);
    }

    // fill(chunk cc) -> buffer cc&1
    auto fill = [&](int cc) {
      float* buf = &xpb[cc & 1][0];
#pragma unroll 2
      for (int i = 0; i < (NCHAIN * TC) / 64; ++i) {  // 8 iters
        const int p = i * 64 + lane;
        const int chain = p >> 3;   // p / TC
        const int t = p & (TC - 1);
        const float4* xr =
            (const float4*)(x + ((size_t)(bid * NCHAIN + chain) * TT +
                                 (cc * TC + t)) * FF);
        float4 a0 = xr[0], a1 = xr[1], a2 = xr[2];
        float4 a3 = xr[3], a4 = xr[4], a5 = xr[5];
        v2f xv[12] = {{a0.x, a0.y}, {a0.z, a0.w}, {a1.x, a1.y}, {a1.z, a1.w},
                      {a2.x, a2.y}, {a2.z, a2.w}, {a3.x, a3.y}, {a3.z, a3.w},
                      {a4.x, a4.y}, {a4.z, a4.w}, {a5.x, a5.y}, {a5.z, a5.w}};
        float* dst = buf + chain * CHSTRIDE + t * ROWF + jbase;
#pragma unroll
        for (int r = 0; r < 4; ++r) {
          v2f s = {0.0f, 0.0f};
#pragma unroll
          for (int k = 0; k < 12; ++k)
            s = __builtin_elementwise_fma(wih[r][k], xv[k], s);
          dst[r] = bs[r] + s.x + s.y;
        }
      }
    };

    fill(0);  // prologue
    for (int c = 0; c < NCHUNK; ++c) {
      __syncthreads();  // publishes buf[c&1]
      if (c + 1 < NCHUNK) fill(c + 1);
    }
  } else {
    // ================= CONSUMER: serial recurrence, 1 chain per lane =================
    v2f whh[12][6];
#pragma unroll
    for (int j = 0; j < 12; ++j)
#pragma unroll
      for (int k = 0; k < 6; ++k)
        whh[j][k] = *(const v2f*)(W_hh + j * HH + 2 * k);

    v2f hv[6];
#pragma unroll
    for (int k = 0; k < 6; ++k) hv[k] = (v2f){0.0f, 0.0f};

    for (int c = 0; c < NCHUNK; ++c) {
      __syncthreads();  // buf[c&1] ready
      const float* bufc = &xpb[c & 1][lane * CHSTRIDE];
      float xc[12], xn[12];
#pragma unroll
      for (int j = 0; j < 12; ++j) xc[j] = bufc[j];  // t=0 (once per chunk)
#pragma unroll
      for (int t = 0; t < TC; ++t) {
        if (t + 1 < TC) {
#pragma unroll
          for (int j = 0; j < 12; ++j) xn[j] = bufc[(t + 1) * ROWF + j];
        }
        float nh[12];
#pragma unroll
        for (int j = 0; j < 12; ++j) {
          v2f s = {0.0f, 0.0f};
#pragma unroll
          for (int k = 0; k < 6; ++k)
            s = __builtin_elementwise_fma(whh[j][k], hv[k], s);
          nh[j] = fast_tanh(xc[j] + s.x + s.y);
        }
#pragma unroll
        for (int k = 0; k < 6; ++k) hv[k] = (v2f){nh[2 * k], nh[2 * k + 1]};
        if (t + 1 < TC) {
#pragma unroll
          for (int j = 0; j < 12; ++j) xc[j] = xn[j];
        }
      }
    }

    // ---------------- MLP head (per chain) ----------------
    float h[12];
#pragma unroll
    for (int k = 0; k < 6; ++k) { h[2 * k] = hv[k].x; h[2 * k + 1] = hv[k].y; }
    float o1[12], o2[12];
#pragma unroll
    for (int i = 0; i < 12; ++i) {
      float acc = b1[i];
#pragma unroll
      for (int j = 0; j < 12; ++j) acc = fmaf(W1[i * 12 + j], h[j], acc);
      o1[i] = fmaxf(acc, 0.0f);
    }
#pragma unroll
    for (int i = 0; i < 12; ++i) {
      float acc = b2[i];
#pragma unroll
      for (int j = 0; j < 12; ++j) acc = fmaf(W2[i * 12 + j], o1[j], acc);
      o2[i] = fmaxf(acc, 0.0f);
    }
    float o = b3[0];
#pragma unroll
    for (int j = 0; j < 12; ++j) o = fmaf(W3[j], o2[j], o);
    out[bid * NCHAIN + lane] = o;
  }
}

extern "C" void kernel_launch(void* const* d_in, const int* in_sizes, int n_in,
                              void* d_out, int out_size, void* d_ws, size_t ws_size,
                              hipStream_t stream) {
  (void)in_sizes; (void)n_in; (void)d_ws; (void)ws_size; (void)out_size;
  const float* x    = (const float*)d_in[0];
  const float* W_ih = (const float*)d_in[1];
  const float* b_ih = (const float*)d_in[2];
  const float* W_hh = (const float*)d_in[3];
  const float* b_hh = (const float*)d_in[4];
  const float* W1   = (const float*)d_in[5];
  const float* b1   = (const float*)d_in[6];
  const float* W2   = (const float*)d_in[7];
  const float* b2   = (const float*)d_in[8];
  const float* W3   = (const float*)d_in[9];
  const float* b3   = (const float*)d_in[10];

  rnn_pc<<<dim3(BB / NCHAIN), dim3(256), 0, stream>>>(
      x, W_ih, b_ih, W_hh, b_hh, W1, b1, W2, b2, W3, b3, (float*)d_out);
}

// Round 3
// 558.179 us; speedup vs baseline: 1.9041x; 1.9041x over previous
//
#include <hip/hip_runtime.h>
#include <stdint.h>

#define BB 8192
#define TT 512
#define FF 24
#define HH 12

#define NCH 32              // chains per block
#define TC 8                // timesteps per chunk
#define NCHUNK (TT / TC)    // 64
#define RS 80               // bytes per (chain,t) xp row in LDS (12 f + 4 zero + 4 pad)
#define CS (TC * RS + 16)   // 656 B per chain per buffer (16-aligned, /4 % 32 == 4)
#define BUFB (NCH * CS)     // 20992 B per buffer

typedef float v16f __attribute__((ext_vector_type(16)));
typedef short v8s __attribute__((ext_vector_type(8)));

__device__ __forceinline__ v16f mf(v8s a, v8s b, v16f c) {
  return __builtin_amdgcn_mfma_f32_32x32x16_bf16(a, b, c, 0, 0, 0);
}
// pack bf16(trunc a) -> low16, bf16(trunc b) -> high16
__device__ __forceinline__ unsigned bhi2(float a, float b) {
  return __builtin_amdgcn_perm(__builtin_bit_cast(unsigned, b),
                               __builtin_bit_cast(unsigned, a), 0x07060302u);
}
__device__ __forceinline__ float lo_res(float x) {  // exact residual of bf16-trunc
  unsigned u = __builtin_bit_cast(unsigned, x) & 0xffff0000u;
  return x - __builtin_bit_cast(float, u);
}
// 8 f32 -> bf16 hi frag + bf16 lo frag (A/B operand order: k ascending, low half first)
__device__ __forceinline__ void mk_frag(const float* v, v8s& hi, v8s& lo) {
  uint4 H, L;
  H.x = bhi2(v[0], v[1]); H.y = bhi2(v[2], v[3]);
  H.z = bhi2(v[4], v[5]); H.w = bhi2(v[6], v[7]);
  float l0 = lo_res(v[0]), l1 = lo_res(v[1]), l2 = lo_res(v[2]), l3 = lo_res(v[3]);
  float l4 = lo_res(v[4]), l5 = lo_res(v[5]), l6 = lo_res(v[6]), l7 = lo_res(v[7]);
  L.x = bhi2(l0, l1); L.y = bhi2(l2, l3); L.z = bhi2(l4, l5); L.w = bhi2(l6, l7);
  hi = __builtin_bit_cast(v8s, H); lo = __builtin_bit_cast(v8s, L);
}
__device__ __forceinline__ float fast_tanh(float x) {
  float e = __expf(x + x);
  float r = __builtin_amdgcn_rcpf(e + 1.0f);
  return fmaf(-2.0f, r, 1.0f);
}

__global__ __launch_bounds__(192, 1) void rnn_mfma(
    const float* __restrict__ x, const float* __restrict__ W_ih,
    const float* __restrict__ b_ih, const float* __restrict__ W_hh,
    const float* __restrict__ b_hh, const float* __restrict__ W1,
    const float* __restrict__ b1, const float* __restrict__ W2,
    const float* __restrict__ b2, const float* __restrict__ W3,
    const float* __restrict__ b3, float* __restrict__ out) {
  __shared__ __align__(16) char xpb[2][BUFB];  // 42 KB

  const int tid = threadIdx.x;
  const int wid = tid >> 6;    // 0,1 producers; 2 consumer
  const int lane = tid & 63;
  const int n = lane & 31;     // MFMA column (chain / row slot)
  const int q = lane >> 5;     // k-half
  const int bid = blockIdx.x;

  // zero both buffers (pad floats 12..15 of every row must be 0)
  {
    float4 z = {0.f, 0.f, 0.f, 0.f};
    float4* p = (float4*)&xpb[0][0];
    for (int i = tid; i < (2 * BUFB) / 16; i += 192) p[i] = z;
  }
  __syncthreads();

  if (wid < 2) {
    // ===================== PRODUCERS: xp = x @ W_ih^T + b_ih + b_hh (via MFMA) =====
    // A1[m][k] = W_ih[m][k] (k 0..15), A2[m][k] = W_ih[m][16+k] (k 0..7), rows >=12 zero.
    v8s A1h, A1l, A2h, A2l;
    {
      float a1[8], a2[8];
      const int m = n;
#pragma unroll
      for (int j = 0; j < 8; ++j) {
        int k1 = 8 * q + j, k2 = 16 + 8 * q + j;
        a1[j] = (m < HH) ? W_ih[m * FF + k1] : 0.f;
        a2[j] = (m < HH && k2 < FF) ? W_ih[m * FF + k2] : 0.f;
      }
      mk_frag(a1, A1h, A1l); mk_frag(a2, A2h, A2l);
    }
    v16f biasC;
#pragma unroll
    for (int r = 0; r < 16; ++r) biasC[r] = 0.f;
#pragma unroll
    for (int r = 0; r < 8; ++r) {
      int m = (r & 3) + 8 * (r >> 2) + 4 * q;
      biasC[r] = (m < HH) ? (b_ih[m] + b_hh[m]) : 0.f;
    }

    const int cL0 = (n >> 3);        // tile-local chain 0..3
    const int trow = n & 7;          // t within chunk
    const unsigned msk = q ? 0u : 0xffffffffu;

    // per chunk: 8 tiles of 32 (chain,t) rows; this wave does tiles 4*wid..4*wid+3
    for (int c = 0; c < NCHUNK; ++c) {
      if (c > 0) __syncthreads();
      const int fc = c;  // fill chunk fc into buffer fc&1 (chunk 0 pre-barrier-loop)
      // preload all 4 tiles (16 float4 in flight)
      float4 pre[4][4];
#pragma unroll
      for (int it = 0; it < 4; ++it) {
        int cL = 16 * wid + 4 * it + cL0;
        const float* rb = x + ((size_t)(bid * NCH + cL) * TT + (fc * TC + trow)) * FF;
        pre[it][0] = *(const float4*)(rb + 8 * q);
        pre[it][1] = *(const float4*)(rb + 8 * q + 4);
        int o2 = q ? 8 : 16;
        pre[it][2] = *(const float4*)(rb + o2);
        pre[it][3] = *(const float4*)(rb + o2 + 4);
      }
#pragma unroll
      for (int it = 0; it < 4; ++it) {
        float xa[8] = {pre[it][0].x, pre[it][0].y, pre[it][0].z, pre[it][0].w,
                       pre[it][1].x, pre[it][1].y, pre[it][1].z, pre[it][1].w};
        float xb[8] = {pre[it][2].x, pre[it][2].y, pre[it][2].z, pre[it][2].w,
                       pre[it][3].x, pre[it][3].y, pre[it][3].z, pre[it][3].w};
        v8s B1h, B1l, B2h, B2l;
        mk_frag(xa, B1h, B1l);
        mk_frag(xb, B2h, B2l);
        // zero B2 on q==1 lanes (k 8..15 of second MFMA = features 24..31 = pad)
        uint4 h2 = __builtin_bit_cast(uint4, B2h), l2 = __builtin_bit_cast(uint4, B2l);
        h2.x &= msk; h2.y &= msk; h2.z &= msk; h2.w &= msk;
        l2.x &= msk; l2.y &= msk; l2.z &= msk; l2.w &= msk;
        B2h = __builtin_bit_cast(v8s, h2); B2l = __builtin_bit_cast(v8s, l2);

        v16f acc = mf(A1h, B1h, biasC);
        acc = mf(A1h, B1l, acc);
        acc = mf(A1l, B1h, acc);
        acc = mf(A2h, B2h, acc);
        acc = mf(A2h, B2l, acc);
        acc = mf(A2l, B2h, acc);

        int cL = 16 * wid + 4 * it + cL0;
        char* rp = &xpb[fc & 1][0] + cL * CS + trow * RS;
        float4 w0 = {acc[0], acc[1], acc[2], acc[3]};
        if (q == 0) {
          *(float4*)(rp) = w0;                                   // xp[0..3]
          float4 w1 = {acc[4], acc[5], acc[6], acc[7]};
          *(float4*)(rp + 32) = w1;                              // xp[8..11]
        } else {
          *(float4*)(rp + 16) = w0;                              // xp[4..7]
        }
      }
    }
    __syncthreads();  // final barrier matching consumer's last chunk
  } else {
    // ===================== CONSUMER: 32 chains, MFMA recurrence ====================
    // A[m][k] = W_hh[rho(m)][k], rho: 0-3->0-3, 4-7->8-11, 8-11->4-7, else 0.
    v8s Ah, Al;
    {
      const int m = n;
      int rho = (m < 4) ? m : (m < 8 ? m + 4 : (m < HH ? m - 4 : -1));
      float wv[8];
#pragma unroll
      for (int j = 0; j < 8; ++j) {
        int k = 8 * q + j;
        wv[j] = (rho >= 0 && k < HH) ? W_hh[rho * HH + k] : 0.f;
      }
      mk_frag(wv, Ah, Al);
    }
    v8s Bh, Bl;
    {
      uint4 z = {0u, 0u, 0u, 0u};
      Bh = __builtin_bit_cast(v8s, z); Bl = __builtin_bit_cast(v8s, z);
    }
    v16f acc;
#pragma unroll
    for (int r = 0; r < 16; ++r) acc[r] = 0.f;
    float h8[8];
#pragma unroll
    for (int j = 0; j < 8; ++j) h8[j] = 0.f;

    for (int c = 0; c < NCHUNK; ++c) {
      __syncthreads();  // buffer c&1 published
      const char* base = &xpb[c & 1][0] + n * CS + q * 32;
#pragma unroll
      for (int t = 0; t < TC; ++t) {
        const float4* p = (const float4*)(base + t * RS);
        float4 ca = p[0], cb = p[1];
        v16f ci = acc;
        ci[0] = ca.x; ci[1] = ca.y; ci[2] = ca.z; ci[3] = ca.w;
        ci[4] = cb.x; ci[5] = cb.y; ci[6] = cb.z; ci[7] = cb.w;
        acc = mf(Ah, Bh, ci);
        acc = mf(Ah, Bl, acc);
        acc = mf(Al, Bh, acc);
#pragma unroll
        for (int j = 0; j < 8; ++j) h8[j] = fast_tanh(acc[j]);
        mk_frag(h8, Bh, Bl);
      }
    }

    // ------------- epilogue: gather h per chain, MLP head -------------
    float* hb = (float*)&xpb[0][0];  // reuse buffer 0 (16 floats per chain)
    if (q == 0) {
#pragma unroll
      for (int j = 0; j < 8; ++j) hb[n * 16 + j] = h8[j];       // h[0..7]
    } else {
#pragma unroll
      for (int j = 0; j < 4; ++j) hb[n * 16 + 8 + j] = h8[j];   // h[8..11]
    }
    __builtin_amdgcn_s_waitcnt(0);  // lgkm drain (same-wave RAW; compiler adds too)
    if (lane < 32) {
      float h[12];
#pragma unroll
      for (int j = 0; j < 12; ++j) h[j] = hb[lane * 16 + j];
      float o1[12], o2[12];
#pragma unroll
      for (int i = 0; i < 12; ++i) {
        float a = b1[i];
#pragma unroll
        for (int j = 0; j < 12; ++j) a = fmaf(W1[i * 12 + j], h[j], a);
        o1[i] = fmaxf(a, 0.f);
      }
#pragma unroll
      for (int i = 0; i < 12; ++i) {
        float a = b2[i];
#pragma unroll
        for (int j = 0; j < 12; ++j) a = fmaf(W2[i * 12 + j], o1[j], a);
        o2[i] = fmaxf(a, 0.f);
      }
      float o = b3[0];
#pragma unroll
      for (int j = 0; j < 12; ++j) o = fmaf(W3[j], o2[j], o);
      out[bid * NCH + lane] = o;
    }
  }
}

extern "C" void kernel_launch(void* const* d_in, const int* in_sizes, int n_in,
                              void* d_out, int out_size, void* d_ws, size_t ws_size,
                              hipStream_t stream) {
  (void)in_sizes; (void)n_in; (void)d_ws; (void)ws_size; (void)out_size;
  const float* x    = (const float*)d_in[0];
  const float* W_ih = (const float*)d_in[1];
  const float* b_ih = (const float*)d_in[2];
  const float* W_hh = (const float*)d_in[3];
  const float* b_hh = (const float*)d_in[4];
  const float* W1   = (const float*)d_in[5];
  const float* b1   = (const float*)d_in[6];
  const float* W2   = (const float*)d_in[7];
  const float* b2   = (const float*)d_in[8];
  const float* W3   = (const float*)d_in[9];
  const float* b3   = (const float*)d_in[10];

  rnn_mfma<<<dim3(BB / NCH), dim3(192), 0, stream>>>(
      x, W_ih, b_ih, W_hh, b_hh, W1, b1, W2, b2, W3, b3, (float*)d_out);
}